// Round 2
// baseline (30813.794 us; speedup 1.0000x reference)
//
#include <hip/hip_runtime.h>
#include <cmath>

// Problem constants
#define T_STEPS 16384
#define D_IN    257
#define H_DIM   512
#define O_DIM   257
#define G4      2048   // 4*H

typedef unsigned long long u64;

// Workspace layout (bytes):
//   [0, 8192)    : u64 msg[2][512]  (double-buffered self-validating h msgs)
//                  msg word i = (tag << 32) | float_bits(h[i])
//   [8192, ...)  : float x_gates[T][2048]
//   then         : float hs[T][512]
#define WS_XG_OFF     8192
#define WS_HS_OFF     (8192 + (size_t)T_STEPS * G4 * 4)

__device__ inline float fast_sigmoid(float x) {
    return 1.f / (1.f + __expf(-x));
}
__device__ inline float fast_tanh(float x) {
    float ax = fminf(fabsf(x), 15.f);
    float e  = __expf(2.f * ax);
    float t  = (e - 1.f) / (e + 1.f);
    return copysignf(t, x);
}
__device__ inline float dot4(float4 a, float4 b) {
    return a.x * b.x + a.y * b.y + a.z * b.z + a.w * b.w;
}

// Register pin: forbid rematerialization of weight loads inside the loop.
#define PIN4(v) asm volatile("" : "+v"(v.x), "+v"(v.y), "+v"(v.z), "+v"(v.w))

// ---------------------------------------------------------------------------
// Phase 1: x_gates[t][j] = sum_k stft[t][k] * W_ih[j][k] + (b_ih[j]+b_hh[j])
// 128x128 tile / 256 threads, k-major LDS so fragments load as float4.
// ---------------------------------------------------------------------------
__global__ __launch_bounds__(256) void xgate_gemm(
    const float* __restrict__ stft, const float* __restrict__ W_ih,
    const float* __restrict__ b_ih, const float* __restrict__ b_hh,
    float* __restrict__ xg)
{
    const int tid = threadIdx.x;
    const int tx = tid & 15, ty = tid >> 4;
    const int j0 = blockIdx.x * 128;
    const int t0 = blockIdx.y * 128;

    __shared__ float s_a[16][132];
    __shared__ float s_b[16][132];

    float acc[8][8] = {};

    for (int k0 = 0; k0 < D_IN; k0 += 16) {
        #pragma unroll
        for (int l = 0; l < 8; ++l) {
            int idx = tid + l * 256;     // 0..2047
            int r   = idx >> 4;          // 0..127
            int kk  = idx & 15;
            int k   = k0 + kk;
            s_a[kk][r] = (k < D_IN) ? stft[(size_t)(t0 + r) * D_IN + k] : 0.f;
            s_b[kk][r] = (k < D_IN) ? W_ih[(size_t)(j0 + r) * D_IN + k] : 0.f;
        }
        __syncthreads();
        #pragma unroll
        for (int kk = 0; kk < 16; ++kk) {
            const float4* pa = (const float4*)&s_a[kk][ty * 8];
            const float4* pb = (const float4*)&s_b[kk][tx * 8];
            float4 a0 = pa[0], a1 = pa[1];
            float4 b0 = pb[0], b1 = pb[1];
            float ar[8] = {a0.x, a0.y, a0.z, a0.w, a1.x, a1.y, a1.z, a1.w};
            float br[8] = {b0.x, b0.y, b0.z, b0.w, b1.x, b1.y, b1.z, b1.w};
            #pragma unroll
            for (int r = 0; r < 8; ++r)
                #pragma unroll
                for (int c = 0; c < 8; ++c)
                    acc[r][c] += ar[r] * br[c];
        }
        __syncthreads();
    }

    float bias[8];
    #pragma unroll
    for (int c = 0; c < 8; ++c) {
        int j = j0 + tx * 8 + c;
        bias[c] = b_ih[j] + b_hh[j];
    }
    #pragma unroll
    for (int r = 0; r < 8; ++r) {
        int t = t0 + ty * 8 + r;
        #pragma unroll
        for (int c = 0; c < 8; ++c) {
            xg[(size_t)t * G4 + j0 + tx * 8 + c] = acc[r][c] + bias[c];
        }
    }
}

// ---------------------------------------------------------------------------
// Phase 2: persistent sequential LSTM, 32 blocks x 1024 threads (16 waves).
//
// Waves 0-7  (main):  identical R0 compute structure. Per step: LDS flag
//   spin (local, ~70cyc period) -> ds_read h slice -> 4 gate partials with
//   weights pinned in registers -> 3-shuffle butterfly -> s_part write ->
//   lgkm-only barrier -> wave0 reduce + activations (applied BEFORE the
//   gate gather; only tanh(c) stays serialized after it) -> publish.
//
// Waves 8-15 (messenger): each lane owns ONE msg word. Its vmcnt contains
//   ONLY poll loads, so counted s_waitcnt vmcnt(3) is exact: 4 same-address
//   global_load_dwordx2 in flight, checked round-robin => sampling period
//   ~L/4 instead of ~L, and no torn reads (8B load vs 8B store is single-
//   copy atomic). Tag check is one v_cmp_lt_u64 vs (t<<32): tags at this
//   address are <= t until this block itself progresses, so >= threshold
//   <=> tag == t. On detect: stage payload into s_h, lgkmcnt(0), lane0
//   raises flag[m]=t, raw s_barrier (no vmcnt drain), keep-alive pins the
//   slot registers so in-flight stale loads land harmlessly.
//
// Barrier accounting: both halves execute exactly one s_barrier per t,
// plus one __syncthreads() before the loops.
// ---------------------------------------------------------------------------
__global__ __launch_bounds__(1024, 1) void lstm_seq(
    const float* __restrict__ W_hh, const float* __restrict__ xg,
    float* __restrict__ hs, u64* __restrict__ msg)
{
    const int tid  = threadIdx.x;        // 0..1023
    const int g    = blockIdx.x;         // 0..31

    __shared__ float s_h[512];
    __shared__ float s_part[2][512];     // [t&1][w*64 + c*16 + j]
    __shared__ int   s_flags[8];

    u64* slot0 = msg;
    u64* slot1 = msg + 512;

    if (tid < 8) s_flags[tid] = -1;
    __syncthreads();

    if (tid < 512) {
        // ------------------------- main waves -------------------------
        const int w    = tid >> 6;           // wave id = col chunk 0..7
        const int lane = tid & 63;
        const int j    = lane >> 2;          // h-index within block
        const int c    = lane & 3;           // 16-col sub-chunk
        const int colb = w * 64 + c * 16;

        const float* wbase = W_hh + (size_t)(g * 16 + j) * H_DIM + colb;
        const size_t gstride = (size_t)H_DIM * H_DIM;
        float4 wA0, wA1, wA2, wA3, wB0, wB1, wB2, wB3;
        float4 wC0, wC1, wC2, wC3, wD0, wD1, wD2, wD3;
        {
            const float4* p0 = (const float4*)(wbase);
            const float4* p1 = (const float4*)(wbase + gstride);
            const float4* p2 = (const float4*)(wbase + 2 * gstride);
            const float4* p3 = (const float4*)(wbase + 3 * gstride);
            wA0 = p0[0]; wA1 = p0[1]; wA2 = p0[2]; wA3 = p0[3];
            wB0 = p1[0]; wB1 = p1[1]; wB2 = p1[2]; wB3 = p1[3];
            wC0 = p2[0]; wC1 = p2[1]; wC2 = p2[2]; wC3 = p2[3];
            wD0 = p3[0]; wD1 = p3[1]; wD2 = p3[2]; wD3 = p3[3];
        }
        PIN4(wA0); PIN4(wA1); PIN4(wA2); PIN4(wA3);
        PIN4(wB0); PIN4(wB1); PIN4(wB2); PIN4(wB3);
        PIN4(wC0); PIN4(wC1); PIN4(wC2); PIN4(wC3);
        PIN4(wD0); PIN4(wD1); PIN4(wD2); PIN4(wD3);

        float c_state = 0.f;
        const int t_j = lane & 15;
        volatile int* fp = (volatile int*)&s_flags[w];

        for (int t = 0; t < T_STEPS; ++t) {
            const int buf = t & 1;

            // Wave 0 prefetches x_gates (independent of h) before the spin.
            float xv = 0.f;
            if (w == 0)
                xv = __builtin_nontemporal_load(
                    xg + (size_t)t * G4 + (lane >> 4) * H_DIM + g * 16 + t_j);

            // Local LDS flag spin: messenger wave w stages s_h[64w..64w+64)
            // then writes flag[w]=t. Monotone tags -> no false release.
            while (*fp != t) {}
            asm volatile("" ::: "memory");

            const float4* hv = (const float4*)(s_h + colb);
            float4 h0 = hv[0], h1 = hv[1], h2 = hv[2], h3 = hv[3];

            float p0 = dot4(wA0, h0) + dot4(wA1, h1) + dot4(wA2, h2) + dot4(wA3, h3);
            float p1 = dot4(wB0, h0) + dot4(wB1, h1) + dot4(wB2, h2) + dot4(wB3, h3);
            float p2 = dot4(wC0, h0) + dot4(wC1, h1) + dot4(wC2, h2) + dot4(wC3, h3);
            float p3 = dot4(wD0, h0) + dot4(wD1, h1) + dot4(wD2, h2) + dot4(wD3, h3);

            const bool lo2 = (c < 2);
            float a0 = (lo2 ? p0 : p2) + __shfl_xor(lo2 ? p2 : p0, 2, 64);
            float a1 = (lo2 ? p1 : p3) + __shfl_xor(lo2 ? p3 : p1, 2, 64);
            const bool ev = ((c & 1) == 0);
            float fin = (ev ? a0 : a1) + __shfl_xor(ev ? a1 : a0, 1, 64);

            s_part[buf][w * 64 + c * 16 + j] = fin;

            // lgkm-only barrier: NO vmcnt drain (stores/loads stay in flight).
            asm volatile("s_waitcnt lgkmcnt(0)\n\ts_barrier" ::: "memory");

            if (w == 0) {
                const float* pp = &s_part[buf][0];
                float sum = xv;
                #pragma unroll
                for (int k = 0; k < 8; ++k) sum += pp[k * 64 + lane];

                // Activate BEFORE the gather: lane's row = (gate=lane>>4, t_j).
                const int gate = lane >> 4;
                float act = (gate == 2) ? fast_tanh(sum) : fast_sigmoid(sum);

                float iv = __shfl(act, t_j + 0,  64);
                float fv = __shfl(act, t_j + 16, 64);
                float gv = __shfl(act, t_j + 32, 64);
                float ov = __shfl(act, t_j + 48, 64);

                c_state = fv * c_state + iv * gv;
                float hn = ov * fast_tanh(c_state);

                if (lane < 16) {
                    u64 m = ((u64)(unsigned)(t + 1) << 32) | (u64)__float_as_uint(hn);
                    u64* wp = (((t + 1) & 1) ? slot1 : slot0) + (g * 16 + lane);
                    __hip_atomic_store(wp, m, __ATOMIC_RELAXED, __HIP_MEMORY_SCOPE_AGENT);
                    __builtin_nontemporal_store(hn, hs + (size_t)t * H_DIM + g * 16 + lane);
                }
            }
            // s_part double-buffered; next write gated by flag(t+1) which
            // requires wave0's publish -> no trailing barrier needed.
        }
    } else {
        // ----------------------- messenger waves -----------------------
        const int widx = tid - 512;          // msg word index 0..511
        const int m    = widx >> 6;          // paired main wave
        const int lane = widx & 63;

        u64 s0 = 0, s1 = 0, s2 = 0, s3 = 0;  // poll slots, live whole loop

        for (int t = 0; t < T_STEPS; ++t) {
            u64* rp = ((t & 1) ? slot1 : slot0) + widx;
            u64 addr = (u64)(uintptr_t)rp;
            u64 th   = ((u64)(unsigned)t) << 32;   // tag<=t here, so >=th <=> tag==t
            int k;

            asm volatile(
                "global_load_dwordx2 %[d0], %[ad], off sc0 sc1\n\t"
                "global_load_dwordx2 %[d1], %[ad], off sc0 sc1\n\t"
                "global_load_dwordx2 %[d2], %[ad], off sc0 sc1\n\t"
                "global_load_dwordx2 %[d3], %[ad], off sc0 sc1\n\t"
                "1:\n\t"
                "s_waitcnt vmcnt(3)\n\t"
                "v_cmp_lt_u64 vcc, %[d0], %[th]\n\t"
                "s_cbranch_vccz 9f\n\t"
                "global_load_dwordx2 %[d0], %[ad], off sc0 sc1\n\t"
                "s_waitcnt vmcnt(3)\n\t"
                "v_cmp_lt_u64 vcc, %[d1], %[th]\n\t"
                "s_cbranch_vccz 8f\n\t"
                "global_load_dwordx2 %[d1], %[ad], off sc0 sc1\n\t"
                "s_waitcnt vmcnt(3)\n\t"
                "v_cmp_lt_u64 vcc, %[d2], %[th]\n\t"
                "s_cbranch_vccz 7f\n\t"
                "global_load_dwordx2 %[d2], %[ad], off sc0 sc1\n\t"
                "s_waitcnt vmcnt(3)\n\t"
                "v_cmp_lt_u64 vcc, %[d3], %[th]\n\t"
                "s_cbranch_vccz 6f\n\t"
                "global_load_dwordx2 %[d3], %[ad], off sc0 sc1\n\t"
                "s_branch 1b\n\t"
                "6:\n\ts_mov_b32 %[k], 3\n\ts_branch 10f\n\t"
                "7:\n\ts_mov_b32 %[k], 2\n\ts_branch 10f\n\t"
                "8:\n\ts_mov_b32 %[k], 1\n\ts_branch 10f\n\t"
                "9:\n\ts_mov_b32 %[k], 0\n\t"
                "10:\n\t"
                : [d0] "+v"(s0), [d1] "+v"(s1), [d2] "+v"(s2), [d3] "+v"(s3),
                  [k] "=&s"(k)
                : [ad] "v"(addr), [th] "s"(th)
                : "vcc", "memory");

            u64 u = (k == 0) ? s0 : (k == 1) ? s1 : (k == 2) ? s2 : s3;

            s_h[widx] = __uint_as_float((unsigned)u);
            asm volatile("s_waitcnt lgkmcnt(0)" ::: "memory");
            if (lane == 0) *(volatile int*)&s_flags[m] = t;

            // Raw barrier: must NOT drain vmcnt (in-flight stale polls OK).
            asm volatile("s_barrier" ::: "memory");
            // Keep slot regs live across the whole iteration so in-flight
            // loads land in pinned registers (values are stale-or-equal,
            // tag < t+1 provably, so next iteration just re-polls).
            asm volatile("" :: "v"(s0), "v"(s1), "v"(s2), "v"(s3));
        }
    }
}

// ---------------------------------------------------------------------------
// Phase 3: out = log_softmax(hs @ W_out^T + b_out)
// ---------------------------------------------------------------------------
__global__ __launch_bounds__(256) void out_softmax(
    const float* __restrict__ hs, const float* __restrict__ W_out,
    const float* __restrict__ b_out, float* __restrict__ out)
{
    const int tid = threadIdx.x;
    const int t0  = blockIdx.x * 16;

    __shared__ float s_w[257 * 33];
    __shared__ float s_hs[16 * 33];
    __shared__ float s_o[16 * 257];
    __shared__ float s_red[8];

    float acc[16] = {};
    float acc256 = 0.f;

    for (int k0 = 0; k0 < H_DIM; k0 += 32) {
        for (int idx = tid; idx < 257 * 32; idx += 256) {
            int row = idx >> 5, col = idx & 31;
            s_w[row * 33 + col] = W_out[(size_t)row * H_DIM + k0 + col];
        }
        for (int idx = tid; idx < 16 * 32; idx += 256) {
            int row = idx >> 5, col = idx & 31;
            s_hs[row * 33 + col] = hs[(size_t)(t0 + row) * H_DIM + k0 + col];
        }
        __syncthreads();
        #pragma unroll
        for (int kk = 0; kk < 32; ++kk) {
            float w = s_w[tid * 33 + kk];
            #pragma unroll
            for (int r = 0; r < 16; ++r)
                acc[r] += s_hs[r * 33 + kk] * w;
        }
        if (tid < 16) {
            #pragma unroll
            for (int kk = 0; kk < 32; ++kk)
                acc256 += s_w[256 * 33 + kk] * s_hs[tid * 33 + kk];
        }
        __syncthreads();
    }

    float bias_c = b_out[tid];
    #pragma unroll
    for (int r = 0; r < 16; ++r) s_o[r * 257 + tid] = acc[r] + bias_c;
    if (tid < 16) s_o[tid * 257 + 256] = acc256 + b_out[256];
    __syncthreads();

    const int lane = tid & 63, wid = tid >> 6;
    for (int r = 0; r < 16; ++r) {
        float v  = s_o[r * 257 + tid];
        float vx = (tid == 0) ? s_o[r * 257 + 256] : -INFINITY;
        float m = fmaxf(v, vx);
        #pragma unroll
        for (int off = 32; off > 0; off >>= 1) m = fmaxf(m, __shfl_xor(m, off, 64));
        if (lane == 0) s_red[wid] = m;
        __syncthreads();
        m = fmaxf(fmaxf(s_red[0], s_red[1]), fmaxf(s_red[2], s_red[3]));
        float e = expf(v - m) + ((tid == 0) ? expf(vx - m) : 0.f);
        #pragma unroll
        for (int off = 32; off > 0; off >>= 1) e += __shfl_xor(e, off, 64);
        if (lane == 0) s_red[4 + wid] = e;
        __syncthreads();
        float s = s_red[4] + s_red[5] + s_red[6] + s_red[7];
        float lg = logf(s) + m;
        out[(size_t)(t0 + r) * O_DIM + tid] = v - lg;
        if (tid == 0) out[(size_t)(t0 + r) * O_DIM + 256] = vx - lg;
    }
}

// ---------------------------------------------------------------------------
extern "C" void kernel_launch(void* const* d_in, const int* in_sizes, int n_in,
                              void* d_out, int out_size, void* d_ws, size_t ws_size,
                              hipStream_t stream) {
    (void)in_sizes; (void)n_in; (void)out_size; (void)ws_size;

    const float* stft  = (const float*)d_in[0];
    const float* W_ih  = (const float*)d_in[1];
    const float* W_hh  = (const float*)d_in[2];
    const float* b_ih  = (const float*)d_in[3];
    const float* b_hh  = (const float*)d_in[4];
    const float* W_out = (const float*)d_in[5];
    const float* b_out = (const float*)d_in[6];
    float* out = (float*)d_out;

    char* ws = (char*)d_ws;
    u64* msg  = (u64*)ws;
    float* xg = (float*)(ws + WS_XG_OFF);
    float* hs = (float*)(ws + WS_HS_OFF);

    // Zero both msg slots (tag 0 + h 0 is exactly the t=0 initial state).
    (void)hipMemsetAsync(ws, 0, 8192, stream);

    xgate_gemm<<<dim3(G4 / 128, T_STEPS / 128), 256, 0, stream>>>(
        stft, W_ih, b_ih, b_hh, xg);
    lstm_seq<<<32, 1024, 0, stream>>>(W_hh, xg, hs, msg);
    out_softmax<<<T_STEPS / 16, 256, 0, stream>>>(hs, W_out, b_out, out);
}

// Round 3
// 27455.667 us; speedup vs baseline: 1.1223x; 1.1223x over previous
//
#include <hip/hip_runtime.h>
#include <cmath>

// Problem constants
#define T_STEPS 16384
#define D_IN    257
#define H_DIM   512
#define O_DIM   257
#define G4      2048   // 4*H
#define NBLK    32     // lstm blocks (= consumers = producers)

typedef unsigned long long u64;

// Workspace layout (bytes):
//   [0, 262144)  : u64 mbox[2][NBLK][512]  (double-buffered, PER-CONSUMER
//                  private mailboxes; word i = (tag<<32)|float_bits(h[i]))
//   [262144, ...): float x_gates[T][2048]
//   then         : float hs[T][512]
#define WS_MSG_BYTES  (2 * NBLK * 512 * 8)       // 262144
#define WS_XG_OFF     WS_MSG_BYTES
#define WS_HS_OFF     (WS_XG_OFF + (size_t)T_STEPS * G4 * 4)
#define MBOX_BUF      (NBLK * 512)               // u64s per buffer

__device__ inline float fast_sigmoid(float x) {
    return 1.f / (1.f + __expf(-x));
}
__device__ inline float fast_tanh(float x) {
    float ax = fminf(fabsf(x), 15.f);
    float e  = __expf(2.f * ax);
    float t  = (e - 1.f) / (e + 1.f);
    return copysignf(t, x);
}
__device__ inline float dot4(float4 a, float4 b) {
    return a.x * b.x + a.y * b.y + a.z * b.z + a.w * b.w;
}

// Register pin: forbid rematerialization of weight loads inside the loop.
#define PIN4(v) asm volatile("" : "+v"(v.x), "+v"(v.y), "+v"(v.z), "+v"(v.w))

// ---------------------------------------------------------------------------
// Phase 1: x_gates[t][j] = sum_k stft[t][k] * W_ih[j][k] + (b_ih[j]+b_hh[j])
// 128x128 tile / 256 threads, k-major LDS so fragments load as float4.
// ---------------------------------------------------------------------------
__global__ __launch_bounds__(256) void xgate_gemm(
    const float* __restrict__ stft, const float* __restrict__ W_ih,
    const float* __restrict__ b_ih, const float* __restrict__ b_hh,
    float* __restrict__ xg)
{
    const int tid = threadIdx.x;
    const int tx = tid & 15, ty = tid >> 4;
    const int j0 = blockIdx.x * 128;
    const int t0 = blockIdx.y * 128;

    __shared__ float s_a[16][132];
    __shared__ float s_b[16][132];

    float acc[8][8] = {};

    for (int k0 = 0; k0 < D_IN; k0 += 16) {
        #pragma unroll
        for (int l = 0; l < 8; ++l) {
            int idx = tid + l * 256;     // 0..2047
            int r   = idx >> 4;          // 0..127
            int kk  = idx & 15;
            int k   = k0 + kk;
            s_a[kk][r] = (k < D_IN) ? stft[(size_t)(t0 + r) * D_IN + k] : 0.f;
            s_b[kk][r] = (k < D_IN) ? W_ih[(size_t)(j0 + r) * D_IN + k] : 0.f;
        }
        __syncthreads();
        #pragma unroll
        for (int kk = 0; kk < 16; ++kk) {
            const float4* pa = (const float4*)&s_a[kk][ty * 8];
            const float4* pb = (const float4*)&s_b[kk][tx * 8];
            float4 a0 = pa[0], a1 = pa[1];
            float4 b0 = pb[0], b1 = pb[1];
            float ar[8] = {a0.x, a0.y, a0.z, a0.w, a1.x, a1.y, a1.z, a1.w};
            float br[8] = {b0.x, b0.y, b0.z, b0.w, b1.x, b1.y, b1.z, b1.w};
            #pragma unroll
            for (int r = 0; r < 8; ++r)
                #pragma unroll
                for (int c = 0; c < 8; ++c)
                    acc[r][c] += ar[r] * br[c];
        }
        __syncthreads();
    }

    float bias[8];
    #pragma unroll
    for (int c = 0; c < 8; ++c) {
        int j = j0 + tx * 8 + c;
        bias[c] = b_ih[j] + b_hh[j];
    }
    #pragma unroll
    for (int r = 0; r < 8; ++r) {
        int t = t0 + ty * 8 + r;
        #pragma unroll
        for (int c = 0; c < 8; ++c) {
            xg[(size_t)t * G4 + j0 + tx * 8 + c] = acc[r][c] + bias[c];
        }
    }
}

// ---------------------------------------------------------------------------
// Phase 2: persistent sequential LSTM — exact R0 structure (best measured),
// with ONE change: PRIVATE per-consumer mailboxes.
//
// R1/R2 post-mortem: all 32 blocks polled the same 64 cache lines; each
// line's LLC bank queued ~32 reads per round-trip and the producer's store
// had to queue behind them. Raising poll rate made it WORSE (24.1 -> 27.3
// -> 30.3 ms), consistent with queueing, not sampling jitter. Fix: block g
// fans out its 16 h-words to 32 private mailboxes (8 fire-and-forget
// dwordx2 stores across wave0's 64 lanes). Consumer c polls only
// mbox[buf][c][tid] — lines read by exactly one wave of one block.
// Poll itself stays the gentle single-outstanding relaxed-agent load.
// ---------------------------------------------------------------------------
__global__ __launch_bounds__(512, 1) void lstm_seq(
    const float* __restrict__ W_hh, const float* __restrict__ xg,
    float* __restrict__ hs, u64* __restrict__ msg)
{
    const int tid  = threadIdx.x;        // 0..511
    const int g    = blockIdx.x;         // 0..31
    const int w    = tid >> 6;           // wave id = col chunk 0..7
    const int lane = tid & 63;
    const int j    = lane >> 2;          // 0..15 h-index within block
    const int c    = lane & 3;           // 0..3 16-col sub-chunk
    const int colb = w * 64 + c * 16;    // this lane's col base

    // Weights: all 4 gate rows of h-index (g*16+j), 16 cols each.
    const float* wbase = W_hh + (size_t)(g * 16 + j) * H_DIM + colb;
    const size_t gstride = (size_t)H_DIM * H_DIM;  // 512*512 between gates
    float4 wA0, wA1, wA2, wA3, wB0, wB1, wB2, wB3;
    float4 wC0, wC1, wC2, wC3, wD0, wD1, wD2, wD3;
    {
        const float4* p0 = (const float4*)(wbase);
        const float4* p1 = (const float4*)(wbase + gstride);
        const float4* p2 = (const float4*)(wbase + 2 * gstride);
        const float4* p3 = (const float4*)(wbase + 3 * gstride);
        wA0 = p0[0]; wA1 = p0[1]; wA2 = p0[2]; wA3 = p0[3];
        wB0 = p1[0]; wB1 = p1[1]; wB2 = p1[2]; wB3 = p1[3];
        wC0 = p2[0]; wC1 = p2[1]; wC2 = p2[2]; wC3 = p2[3];
        wD0 = p3[0]; wD1 = p3[1]; wD2 = p3[2]; wD3 = p3[3];
    }
    PIN4(wA0); PIN4(wA1); PIN4(wA2); PIN4(wA3);
    PIN4(wB0); PIN4(wB1); PIN4(wB2); PIN4(wB3);
    PIN4(wC0); PIN4(wC1); PIN4(wC2); PIN4(wC3);
    PIN4(wD0); PIN4(wD1); PIN4(wD2); PIN4(wD3);

    __shared__ float s_h[512];           // wave w stages+reads [64w,64w+64) only
    __shared__ float s_part[2][512];     // [t&1][w*64 + c*16 + j]

    // This block's private poll region, per buffer.
    u64* my0 = msg + (size_t)g * 512;
    u64* my1 = msg + MBOX_BUF + (size_t)g * 512;

    float c_state = 0.f;                 // wave0: state for j'=lane&15 (x4 repl)
    const int t_j = lane & 15;           // wave0 tail: h-index within block

    for (int t = 0; t < T_STEPS; ++t) {
        const unsigned tagt = (unsigned)t;
        const int buf = t & 1;

        // Wave 0 prefetches x_gates (independent of h) before the spin.
        // Nontemporal: read-once stream must not evict msg lines from LLC.
        float xv = 0.f;
        if (w == 0)
            xv = __builtin_nontemporal_load(
                xg + (size_t)t * G4 + (lane >> 4) * H_DIM + g * 16 + t_j);

        // Poll own single message word (private line set): tag==t validates
        // payload in-load. Single-outstanding — gentle on the LLC.
        u64* rp = (buf ? my1 : my0) + tid;
        u64 u;
        for (;;) {
            u = __hip_atomic_load(rp, __ATOMIC_RELAXED, __HIP_MEMORY_SCOPE_AGENT);
            if ((unsigned)(u >> 32) == tagt) break;
        }

        // Intra-wave h staging: wave w only touches its own 64-word region.
        s_h[tid] = __uint_as_float((unsigned)u);

        // h slice for this lane: 16 floats (4x b128, broadcast across j).
        const float4* hv = (const float4*)(s_h + colb);
        float4 h0 = hv[0], h1 = hv[1], h2 = hv[2], h3 = hv[3];

        // 4 gate partials over this lane's 16 cols (weights in registers).
        float p0 = dot4(wA0, h0) + dot4(wA1, h1) + dot4(wA2, h2) + dot4(wA3, h3);
        float p1 = dot4(wB0, h0) + dot4(wB1, h1) + dot4(wB2, h2) + dot4(wB3, h3);
        float p2 = dot4(wC0, h0) + dot4(wC1, h1) + dot4(wC2, h2) + dot4(wC3, h3);
        float p3 = dot4(wD0, h0) + dot4(wD1, h1) + dot4(wD2, h2) + dot4(wD3, h3);

        // Exchange-half butterfly over the 4 c-lanes: lane c ends with the
        // full 64-col sum of gate c. 3 shuffles total.
        const bool lo2 = (c < 2);
        float a0 = (lo2 ? p0 : p2) + __shfl_xor(lo2 ? p2 : p0, 2, 64);
        float a1 = (lo2 ? p1 : p3) + __shfl_xor(lo2 ? p3 : p1, 2, 64);
        const bool ev = ((c & 1) == 0);
        float fin = (ev ? a0 : a1) + __shfl_xor(ev ? a1 : a0, 1, 64);

        // Write this wave's partial for row (gate=c, j): 2-way banks = free.
        s_part[buf][w * 64 + c * 16 + j] = fin;

        // lgkm-only barrier: LDS writes visible; NO vmcnt drain (publish
        // stores and xg loads stay in flight).
        asm volatile("s_waitcnt lgkmcnt(0)\n\ts_barrier" ::: "memory");

        if (w == 0) {
            // Sum the 8 per-wave partials for this lane's row (r = lane).
            const float* pp = &s_part[buf][0];
            float sum = xv;
            #pragma unroll
            for (int k = 0; k < 8; ++k) sum += pp[k * 64 + lane];

            // Gather the 4 gates of h-index t_j (rows t_j, +16, +32, +48).
            float gi = __shfl(sum, t_j + 0,  64);
            float gf = __shfl(sum, t_j + 16, 64);
            float gg = __shfl(sum, t_j + 32, 64);
            float go = __shfl(sum, t_j + 48, 64);

            float iv = fast_sigmoid(gi);
            float fv = fast_sigmoid(gf);
            float ov = fast_sigmoid(go);
            float gv = fast_tanh(gg);
            c_state = fv * c_state + iv * gv;     // identical on the 4 gate-lanes
            float hn = ov * fast_tanh(c_state);

            // Fan-out publish: all 64 lanes hold hn for h-index t_j.
            // Lane l serves consumers (l>>4)+4k, k=0..7: 8 dwordx2 stores,
            // each inst covering 4 consumers x 128B contiguous.
            u64 m = ((u64)(tagt + 1) << 32) | (u64)__float_as_uint(hn);
            u64* wb = msg + (((t + 1) & 1) ? MBOX_BUF : 0);
            const int widx = g * 16 + t_j;
            #pragma unroll
            for (int k = 0; k < 8; ++k) {
                int cdst = (lane >> 4) + 4 * k;
                __hip_atomic_store(wb + (size_t)cdst * 512 + widx, m,
                                   __ATOMIC_RELAXED, __HIP_MEMORY_SCOPE_AGENT);
            }
            if (lane < 16) {
                // Coalesced 16-dword nontemporal stream store of h history.
                __builtin_nontemporal_store(hn, hs + (size_t)t * H_DIM + g * 16 + lane);
            }
        }
        // No trailing barrier: s_h is intra-wave; s_part double-buffered —
        // its re-write at t+2 is gated by the barrier at t+1, which wave 0
        // only reaches after finishing its reads of s_part[t&1].
    }
}

// ---------------------------------------------------------------------------
// Phase 3: out = log_softmax(hs @ W_out^T + b_out)
// ---------------------------------------------------------------------------
__global__ __launch_bounds__(256) void out_softmax(
    const float* __restrict__ hs, const float* __restrict__ W_out,
    const float* __restrict__ b_out, float* __restrict__ out)
{
    const int tid = threadIdx.x;
    const int t0  = blockIdx.x * 16;

    __shared__ float s_w[257 * 33];
    __shared__ float s_hs[16 * 33];
    __shared__ float s_o[16 * 257];
    __shared__ float s_red[8];

    float acc[16] = {};
    float acc256 = 0.f;

    for (int k0 = 0; k0 < H_DIM; k0 += 32) {
        for (int idx = tid; idx < 257 * 32; idx += 256) {
            int row = idx >> 5, col = idx & 31;
            s_w[row * 33 + col] = W_out[(size_t)row * H_DIM + k0 + col];
        }
        for (int idx = tid; idx < 16 * 32; idx += 256) {
            int row = idx >> 5, col = idx & 31;
            s_hs[row * 33 + col] = hs[(size_t)(t0 + row) * H_DIM + k0 + col];
        }
        __syncthreads();
        #pragma unroll
        for (int kk = 0; kk < 32; ++kk) {
            float w = s_w[tid * 33 + kk];
            #pragma unroll
            for (int r = 0; r < 16; ++r)
                acc[r] += s_hs[r * 33 + kk] * w;
        }
        if (tid < 16) {
            #pragma unroll
            for (int kk = 0; kk < 32; ++kk)
                acc256 += s_w[256 * 33 + kk] * s_hs[tid * 33 + kk];
        }
        __syncthreads();
    }

    float bias_c = b_out[tid];
    #pragma unroll
    for (int r = 0; r < 16; ++r) s_o[r * 257 + tid] = acc[r] + bias_c;
    if (tid < 16) s_o[tid * 257 + 256] = acc256 + b_out[256];
    __syncthreads();

    const int lane = tid & 63, wid = tid >> 6;
    for (int r = 0; r < 16; ++r) {
        float v  = s_o[r * 257 + tid];
        float vx = (tid == 0) ? s_o[r * 257 + 256] : -INFINITY;
        float m = fmaxf(v, vx);
        #pragma unroll
        for (int off = 32; off > 0; off >>= 1) m = fmaxf(m, __shfl_xor(m, off, 64));
        if (lane == 0) s_red[wid] = m;
        __syncthreads();
        m = fmaxf(fmaxf(s_red[0], s_red[1]), fmaxf(s_red[2], s_red[3]));
        float e = expf(v - m) + ((tid == 0) ? expf(vx - m) : 0.f);
        #pragma unroll
        for (int off = 32; off > 0; off >>= 1) e += __shfl_xor(e, off, 64);
        if (lane == 0) s_red[4 + wid] = e;
        __syncthreads();
        float s = s_red[4] + s_red[5] + s_red[6] + s_red[7];
        float lg = logf(s) + m;
        out[(size_t)(t0 + r) * O_DIM + tid] = v - lg;
        if (tid == 0) out[(size_t)(t0 + r) * O_DIM + 256] = vx - lg;
    }
}

// ---------------------------------------------------------------------------
extern "C" void kernel_launch(void* const* d_in, const int* in_sizes, int n_in,
                              void* d_out, int out_size, void* d_ws, size_t ws_size,
                              hipStream_t stream) {
    (void)in_sizes; (void)n_in; (void)out_size; (void)ws_size;

    const float* stft  = (const float*)d_in[0];
    const float* W_ih  = (const float*)d_in[1];
    const float* W_hh  = (const float*)d_in[2];
    const float* b_ih  = (const float*)d_in[3];
    const float* b_hh  = (const float*)d_in[4];
    const float* W_out = (const float*)d_in[5];
    const float* b_out = (const float*)d_in[6];
    float* out = (float*)d_out;

    char* ws = (char*)d_ws;
    u64* msg  = (u64*)ws;
    float* xg = (float*)(ws + WS_XG_OFF);
    float* hs = (float*)(ws + WS_HS_OFF);

    // Zero both mailbox buffers (tag 0 + h 0 is exactly the t=0 state).
    (void)hipMemsetAsync(ws, 0, WS_MSG_BYTES, stream);

    xgate_gemm<<<dim3(G4 / 128, T_STEPS / 128), 256, 0, stream>>>(
        stft, W_ih, b_ih, b_hh, xg);
    lstm_seq<<<NBLK, 512, 0, stream>>>(W_hh, xg, hs, msg);
    out_softmax<<<T_STEPS / 16, 256, 0, stream>>>(hs, W_out, b_out, out);
}